// Round 2
// baseline (458.819 us; speedup 1.0000x reference)
//
#include <hip/hip_runtime.h>
#include <hip/hip_bf16.h>
#include <math.h>

#define BB    4
#define NTOK  4096
#define CC    256
#define NH    4
#define HD    64
#define MM_KV 1024
#define CKV   128

// ---------------------------------------------------------------------------
// conv1x1 + BN(eval) + SiLU as tiled GEMM:
// Out[b,o,p] = silu( (sum_c W[o,c]*X[b,c,p]) * g[o] + b2[o] )
// X: (B,256,4096) flat, W: (COUT,256), Out: (B,COUT,4096)
// ---------------------------------------------------------------------------
template<int COUT>
__global__ __launch_bounds__(256) void conv_bn_silu_kernel(
    const float* __restrict__ X, const float* __restrict__ W,
    const float* __restrict__ gamma, const float* __restrict__ beta,
    const float* __restrict__ mean,  const float* __restrict__ var,
    float* __restrict__ Y)
{
  const int b  = blockIdx.z;
  const int ot = blockIdx.y;   // 64-wide o tile
  const int pt = blockIdx.x;   // 64-wide p tile
  __shared__ float Ws[32][68]; // [k][o]
  __shared__ float Xs[32][68]; // [k][p]
  const int t  = threadIdx.x;
  const int ty = t >> 4, tx = t & 15;
  const float* Xb = X + (size_t)b * (CC * NTOK) + pt * 64;
  const float* Wb = W + ot * 64 * CC;
  float acc[4][4] = {};
  for (int c0 = 0; c0 < CC; c0 += 32) {
    #pragma unroll
    for (int i = 0; i < 8; ++i) {
      int e = t + i * 256;            // 2048 = 64o x 32k
      int o = e >> 5, k = e & 31;
      Ws[k][o] = Wb[o * CC + c0 + k];
    }
    #pragma unroll
    for (int i = 0; i < 8; ++i) {
      int e = t + i * 256;            // 2048 = 32k x 64p
      int k = e >> 6, p = e & 63;
      Xs[k][p] = Xb[(size_t)(c0 + k) * NTOK + p];
    }
    __syncthreads();
    #pragma unroll
    for (int k = 0; k < 32; ++k) {
      float4 wv = *(const float4*)&Ws[k][ty * 4];
      float4 xv = *(const float4*)&Xs[k][tx * 4];
      float a4[4] = {wv.x, wv.y, wv.z, wv.w};
      float b4[4] = {xv.x, xv.y, xv.z, xv.w};
      #pragma unroll
      for (int i = 0; i < 4; ++i)
        #pragma unroll
        for (int j = 0; j < 4; ++j)
          acc[i][j] = fmaf(a4[i], b4[j], acc[i][j]);
    }
    __syncthreads();
  }
  #pragma unroll
  for (int i = 0; i < 4; ++i) {
    int o = ot * 64 + ty * 4 + i;
    float g  = gamma[o] * rsqrtf(var[o] + 1e-5f);
    float b2 = beta[o] - mean[o] * g;
    float r[4];
    #pragma unroll
    for (int j = 0; j < 4; ++j) {
      float v = acc[i][j] * g + b2;
      r[j] = v / (1.f + __expf(-v));
    }
    float4 o4 = make_float4(r[0], r[1], r[2], r[3]);
    *(float4*)&Y[(size_t)b * COUT * NTOK + (size_t)o * NTOK + pt * 64 + tx * 4] = o4;
  }
}

// ---------------------------------------------------------------------------
// Flash attention over the scrambled conv outputs.
// Q rows: Qbn[b, n>>4, (n&15)*256 + h*64 + d]  (64 contiguous floats)
// K rows: KVbn[b, m>>3, (m&7)*512 + h*64 + d]; V rows: +256
// Output: O[b][h][n][d] row-major (== out2 flat for the projection)
// ---------------------------------------------------------------------------
__device__ __forceinline__ int swz(int row, int c4) {
  return c4 ^ ((row & 3) ^ ((row >> 2) & 7));
}

__global__ __launch_bounds__(256) void attn_kernel(
    const float* __restrict__ Q,   // (B,256,4096)
    const float* __restrict__ KV,  // (B,128,4096)
    float* __restrict__ O)         // (B,NH,NTOK,HD)
{
  const int nt = blockIdx.x;   // 64-row n tile
  const int hh = blockIdx.y;
  const int b  = blockIdx.z;
  const int n0 = nt * 64;
  __shared__ float4 Qs[64 * 16];
  __shared__ float4 Ks[64 * 16];
  __shared__ float4 Vs[64 * 16];
  __shared__ float4 Ps[64 * 16];
  const int t  = threadIdx.x;
  const int rg = t >> 4;   // 0..15: row group (4 rows)
  const int mg = t & 15;   // 0..15: m group / d group (4 cols)

  const float* Qb  = Q  + (size_t)b * (CC * NTOK)  + hh * 64;
  const float* KVb = KV + (size_t)b * (CKV * NTOK) + hh * 64;

  // stage Q tile (64 rows x 64 d), swizzled float4 chunks
  #pragma unroll
  for (int i = 0; i < 4; ++i) {
    int e = t + i * 256;          // 1024 = 64r x 16chunks
    int r = e >> 4, d4 = e & 15;
    int n = n0 + r;
    const float* src = Qb + ((n >> 4) * 4096 + (n & 15) * 256) + d4 * 4;
    Qs[r * 16 + swz(r, d4)] = *(const float4*)src;
  }

  float m_run[4], l_run[4], acc[4][4];
  #pragma unroll
  for (int i = 0; i < 4; ++i) {
    m_run[i] = -1e30f; l_run[i] = 0.f;
    #pragma unroll
    for (int j = 0; j < 4; ++j) acc[i][j] = 0.f;
  }

  for (int mt = 0; mt < 16; ++mt) {
    // stage K/V tile (64 keys)
    #pragma unroll
    for (int i = 0; i < 4; ++i) {
      int e = t + i * 256;
      int mrow = e >> 4, d4 = e & 15;
      int m = mt * 64 + mrow;
      const float* kb = KVb + ((m >> 3) * 4096 + (m & 7) * 512) + d4 * 4;
      Ks[mrow * 16 + swz(mrow, d4)] = *(const float4*)kb;
      Vs[mrow * 16 + swz(mrow, d4)] = *(const float4*)(kb + 256);
    }
    __syncthreads();

    // scores: rows rg*4+i, key cols mg*4+j
    float s[4][4] = {};
    #pragma unroll
    for (int d4 = 0; d4 < 16; ++d4) {
      float4 qv[4], kv[4];
      #pragma unroll
      for (int i = 0; i < 4; ++i) qv[i] = Qs[(rg * 4 + i) * 16 + swz(rg * 4 + i, d4)];
      #pragma unroll
      for (int j = 0; j < 4; ++j) kv[j] = Ks[(mg * 4 + j) * 16 + swz(mg * 4 + j, d4)];
      #pragma unroll
      for (int i = 0; i < 4; ++i)
        #pragma unroll
        for (int j = 0; j < 4; ++j) {
          s[i][j] = fmaf(qv[i].x, kv[j].x, s[i][j]);
          s[i][j] = fmaf(qv[i].y, kv[j].y, s[i][j]);
          s[i][j] = fmaf(qv[i].z, kv[j].z, s[i][j]);
          s[i][j] = fmaf(qv[i].w, kv[j].w, s[i][j]);
        }
    }

    // online softmax update (rows replicated across the 16 mg lanes)
    #pragma unroll
    for (int i = 0; i < 4; ++i) {
      #pragma unroll
      for (int j = 0; j < 4; ++j) s[i][j] *= 0.125f;
      float tm = fmaxf(fmaxf(s[i][0], s[i][1]), fmaxf(s[i][2], s[i][3]));
      #pragma unroll
      for (int off = 1; off < 16; off <<= 1) tm = fmaxf(tm, __shfl_xor(tm, off, 64));
      float mnew = fmaxf(m_run[i], tm);
      float corr = __expf(m_run[i] - mnew);
      float rs = 0.f;
      #pragma unroll
      for (int j = 0; j < 4; ++j) { s[i][j] = __expf(s[i][j] - mnew); rs += s[i][j]; }
      #pragma unroll
      for (int off = 1; off < 16; off <<= 1) rs += __shfl_xor(rs, off, 64);
      l_run[i] = l_run[i] * corr + rs;
      m_run[i] = mnew;
      #pragma unroll
      for (int j = 0; j < 4; ++j) acc[i][j] *= corr;
      Ps[(rg * 4 + i) * 16 + swz(rg * 4 + i, mg)] = make_float4(s[i][0], s[i][1], s[i][2], s[i][3]);
    }
    __syncthreads();

    // PV: acc[i][dj] += sum_m P[row][m] * V[m][mg*4+dj]
    #pragma unroll
    for (int m4 = 0; m4 < 16; ++m4) {
      float4 pp[4], vv[4];
      #pragma unroll
      for (int i = 0; i < 4; ++i) pp[i] = Ps[(rg * 4 + i) * 16 + swz(rg * 4 + i, m4)];
      #pragma unroll
      for (int j = 0; j < 4; ++j) vv[j] = Vs[(m4 * 4 + j) * 16 + swz(m4 * 4 + j, mg)];
      #pragma unroll
      for (int i = 0; i < 4; ++i) {
        float p4[4] = {pp[i].x, pp[i].y, pp[i].z, pp[i].w};
        #pragma unroll
        for (int j = 0; j < 4; ++j) {
          acc[i][0] = fmaf(p4[j], vv[j].x, acc[i][0]);
          acc[i][1] = fmaf(p4[j], vv[j].y, acc[i][1]);
          acc[i][2] = fmaf(p4[j], vv[j].z, acc[i][2]);
          acc[i][3] = fmaf(p4[j], vv[j].w, acc[i][3]);
        }
      }
    }
    __syncthreads();
  }

  #pragma unroll
  for (int i = 0; i < 4; ++i) {
    int r = rg * 4 + i;
    float inv = 1.f / l_run[i];
    float4 o4 = make_float4(acc[i][0] * inv, acc[i][1] * inv, acc[i][2] * inv, acc[i][3] * inv);
    size_t off = (((size_t)(b * NH + hh) * NTOK) + n0 + r) * HD + mg * 4;
    *(float4*)&O[off] = o4;
  }
}

// ---------------------------------------------------------------------------
// projection: Out[r,co] = sum_ci A[r,ci]*Wp[co,ci] + bias[co]
// A: (16384,256) row-major (= attention output flat), Out: (16384,256)
// ---------------------------------------------------------------------------
__global__ __launch_bounds__(256) void proj_kernel(
    const float* __restrict__ A, const float* __restrict__ Wp,
    const float* __restrict__ bias, float* __restrict__ Out)
{
  const int rt = blockIdx.x;   // 256 tiles of 64 rows
  const int ct = blockIdx.y;   // 4 tiles of 64 cols
  __shared__ float As[32][68]; // [k][r]
  __shared__ float Ws[32][68]; // [k][co]
  const int t  = threadIdx.x;
  const int ty = t >> 4, tx = t & 15;
  float acc[4][4] = {};
  const float* Ab = A  + (size_t)rt * 64 * 256;
  const float* Wb = Wp + (size_t)ct * 64 * 256;
  for (int c0 = 0; c0 < 256; c0 += 32) {
    #pragma unroll
    for (int i = 0; i < 8; ++i) {
      int e = t + i * 256;
      int r = e >> 5, k = e & 31;
      As[k][r] = Ab[r * 256 + c0 + k];
      Ws[k][r] = Wb[r * 256 + c0 + k];
    }
    __syncthreads();
    #pragma unroll
    for (int k = 0; k < 32; ++k) {
      float4 av = *(const float4*)&As[k][ty * 4];
      float4 wv = *(const float4*)&Ws[k][tx * 4];
      float a4[4] = {av.x, av.y, av.z, av.w};
      float b4[4] = {wv.x, wv.y, wv.z, wv.w};
      #pragma unroll
      for (int i = 0; i < 4; ++i)
        #pragma unroll
        for (int j = 0; j < 4; ++j)
          acc[i][j] = fmaf(a4[i], b4[j], acc[i][j]);
    }
    __syncthreads();
  }
  #pragma unroll
  for (int i = 0; i < 4; ++i) {
    int r = rt * 64 + ty * 4 + i;
    float o[4];
    #pragma unroll
    for (int j = 0; j < 4; ++j) o[j] = acc[i][j] + bias[ct * 64 + tx * 4 + j];
    float4 o4 = make_float4(o[0], o[1], o[2], o[3]);
    *(float4*)&Out[(size_t)r * 256 + ct * 64 + tx * 4] = o4;
  }
}

// ---------------------------------------------------------------------------
extern "C" void kernel_launch(void* const* d_in, const int* in_sizes, int n_in,
                              void* d_out, int out_size, void* d_ws, size_t ws_size,
                              hipStream_t stream) {
  const float* x        = (const float*)d_in[0];
  const float* y        = (const float*)d_in[1];
  // d_in[2]=H, d_in[3]=W (ints, fixed 64x64 for this problem)
  const float* q_w      = (const float*)d_in[4];
  const float* q_gamma  = (const float*)d_in[5];
  const float* q_beta   = (const float*)d_in[6];
  const float* q_mean   = (const float*)d_in[7];
  const float* q_var    = (const float*)d_in[8];
  const float* kv_w     = (const float*)d_in[9];
  const float* kv_gamma = (const float*)d_in[10];
  const float* kv_beta  = (const float*)d_in[11];
  const float* kv_mean  = (const float*)d_in[12];
  const float* kv_var   = (const float*)d_in[13];
  const float* proj_w   = (const float*)d_in[14];
  const float* proj_b   = (const float*)d_in[15];
  float* out = (float*)d_out;

  float* qbn    = (float*)d_ws;                         // B*256*4096 floats
  float* kvbn   = qbn  + (size_t)BB * CC * NTOK;        // B*128*4096 floats
  float* attout = kvbn + (size_t)BB * CKV * NTOK;       // B*4*4096*64 floats

  conv_bn_silu_kernel<256><<<dim3(64, 4, BB), 256, 0, stream>>>(
      x, q_w, q_gamma, q_beta, q_mean, q_var, qbn);
  conv_bn_silu_kernel<128><<<dim3(64, 2, BB), 256, 0, stream>>>(
      y, kv_w, kv_gamma, kv_beta, kv_mean, kv_var, kvbn);
  attn_kernel<<<dim3(64, NH, BB), 256, 0, stream>>>(qbn, kvbn, attout);
  proj_kernel<<<dim3(256, 4, 1), 256, 0, stream>>>(attout, proj_w, proj_b, out);
}

// Round 3
// 161.864 us; speedup vs baseline: 2.8346x; 2.8346x over previous
//
#include <hip/hip_runtime.h>
#include <hip/hip_bf16.h>
#include <math.h>

#define BB    4
#define NTOK  4096
#define CC    256
#define NH    4
#define HD    64
#define CKV   128

typedef _Float16 half8 __attribute__((ext_vector_type(8)));
typedef float    f32x4 __attribute__((ext_vector_type(4)));

// ---------------------------------------------------------------------------
// conv1x1 + BN(eval) + SiLU as tiled GEMM (fp32, unchanged from baseline)
// ---------------------------------------------------------------------------
template<int COUT>
__global__ __launch_bounds__(256) void conv_bn_silu_kernel(
    const float* __restrict__ X, const float* __restrict__ W,
    const float* __restrict__ gamma, const float* __restrict__ beta,
    const float* __restrict__ mean,  const float* __restrict__ var,
    float* __restrict__ Y)
{
  const int b  = blockIdx.z;
  const int ot = blockIdx.y;
  const int pt = blockIdx.x;
  __shared__ float Ws[32][68];
  __shared__ float Xs[32][68];
  const int t  = threadIdx.x;
  const int ty = t >> 4, tx = t & 15;
  const float* Xb = X + (size_t)b * (CC * NTOK) + pt * 64;
  const float* Wb = W + ot * 64 * CC;
  float acc[4][4] = {};
  for (int c0 = 0; c0 < CC; c0 += 32) {
    #pragma unroll
    for (int i = 0; i < 8; ++i) {
      int e = t + i * 256;
      int o = e >> 5, k = e & 31;
      Ws[k][o] = Wb[o * CC + c0 + k];
    }
    #pragma unroll
    for (int i = 0; i < 8; ++i) {
      int e = t + i * 256;
      int k = e >> 6, p = e & 63;
      Xs[k][p] = Xb[(size_t)(c0 + k) * NTOK + p];
    }
    __syncthreads();
    #pragma unroll
    for (int k = 0; k < 32; ++k) {
      float4 wv = *(const float4*)&Ws[k][ty * 4];
      float4 xv = *(const float4*)&Xs[k][tx * 4];
      float a4[4] = {wv.x, wv.y, wv.z, wv.w};
      float b4[4] = {xv.x, xv.y, xv.z, xv.w};
      #pragma unroll
      for (int i = 0; i < 4; ++i)
        #pragma unroll
        for (int j = 0; j < 4; ++j)
          acc[i][j] = fmaf(a4[i], b4[j], acc[i][j]);
    }
    __syncthreads();
  }
  #pragma unroll
  for (int i = 0; i < 4; ++i) {
    int o = ot * 64 + ty * 4 + i;
    float g  = gamma[o] * rsqrtf(var[o] + 1e-5f);
    float b2 = beta[o] - mean[o] * g;
    float r[4];
    #pragma unroll
    for (int j = 0; j < 4; ++j) {
      float v = acc[i][j] * g + b2;
      r[j] = v / (1.f + __expf(-v));
    }
    float4 o4 = make_float4(r[0], r[1], r[2], r[3]);
    *(float4*)&Y[(size_t)b * COUT * NTOK + (size_t)o * NTOK + pt * 64 + tx * 4] = o4;
  }
}

// ---------------------------------------------------------------------------
// fp16 MFMA flash attention.
// Q rows: Qbn[b, n>>4, (n&15)*256 + h*64 + d]  (64 contiguous fp32)
// K rows: KVbn[b, m>>3, (m&7)*512 + h*64 + d]; V rows: +256
// Block: 4 waves x 32 q-rows = 128 q-rows; KV tiles of 64.
// Fragment maps (16x16x32): A[m=lane&15][k=(lane>>4)*8+i],
// B[k=(lane>>4)*8+i][n=lane&15], D[row=(lane>>4)*4+reg][col=lane&15].
// LDS rows XOR-swizzled: half_idx ^= (row&7)<<3 -> all ds_read_b128 conflict-free.
// ---------------------------------------------------------------------------
__device__ __forceinline__ int swzi(int row, int d) {
  return row * 64 + (d ^ ((row & 7) << 3));
}

__global__ __launch_bounds__(256) void attn_mfma_kernel(
    const float* __restrict__ Q,   // (B,256,4096) fp32
    const float* __restrict__ KV,  // (B,128,4096) fp32
    float* __restrict__ O)         // (B,NH,NTOK,HD) fp32
{
  const int nt = blockIdx.x, hh = blockIdx.y, b = blockIdx.z;
  const int n0 = nt * 128;
  const int t = threadIdx.x;
  const int wave = t >> 6, lane = t & 63;
  const int lm = lane & 15, lg = lane >> 4;

  __shared__ _Float16 Klds[64 * 64];
  __shared__ _Float16 Vt[64 * 64];    // V transposed: Vt[dv][k]
  __shared__ _Float16 QP[128 * 64];   // Q staging, then per-wave P slices

  const float* Qb  = Q  + (size_t)b * (CC * NTOK)  + hh * 64;
  const float* KVb = KV + (size_t)b * (CKV * NTOK) + hh * 64;

  // ---- stage Q (128 rows x 64 d) as fp16, swizzled
  #pragma unroll
  for (int it = 0; it < 4; ++it) {
    int s = t + it * 256;
    int q = s >> 3, d0 = (s & 7) * 8;
    int n = n0 + q;
    const float* src = Qb + (n >> 4) * 4096 + (n & 15) * 256 + d0;
    float4 a = *(const float4*)src;
    float4 c = *(const float4*)(src + 4);
    half8 h;
    h[0]=(_Float16)a.x; h[1]=(_Float16)a.y; h[2]=(_Float16)a.z; h[3]=(_Float16)a.w;
    h[4]=(_Float16)c.x; h[5]=(_Float16)c.y; h[6]=(_Float16)c.z; h[7]=(_Float16)c.w;
    *(half8*)&QP[swzi(q, d0)] = h;
  }
  __syncthreads();

  // ---- load Q fragments (this wave's 32 rows), then QP slice becomes P
  const int wq = wave * 32;
  half8 qf[2][2];
  #pragma unroll
  for (int qg = 0; qg < 2; ++qg)
    #pragma unroll
    for (int ds = 0; ds < 2; ++ds)
      qf[qg][ds] = *(half8*)&QP[swzi(wq + qg * 16 + lm, ds * 32 + lg * 8)];

  f32x4 acc[2][4];
  float m_run[2][4], l_run[2][4];
  #pragma unroll
  for (int qg = 0; qg < 2; ++qg) {
    #pragma unroll
    for (int r = 0; r < 4; ++r) { m_run[qg][r] = -1e30f; l_run[qg][r] = 0.f; }
    #pragma unroll
    for (int dg = 0; dg < 4; ++dg) acc[qg][dg] = (f32x4){0.f, 0.f, 0.f, 0.f};
  }

  for (int mt = 0; mt < 16; ++mt) {
    __syncthreads();   // prev K/Vt consumers done (and Q-frag loads on iter 0)
    // ---- stage K tile (64 keys x 64 d)
    #pragma unroll
    for (int it = 0; it < 2; ++it) {
      int s = t + it * 256;
      int key = s >> 3, d0 = (s & 7) * 8;
      const float* src = KVb + (size_t)(mt * 8 + (key >> 3)) * 4096 + (key & 7) * 512 + d0;
      float4 a = *(const float4*)src;
      float4 c = *(const float4*)(src + 4);
      half8 h;
      h[0]=(_Float16)a.x; h[1]=(_Float16)a.y; h[2]=(_Float16)a.z; h[3]=(_Float16)a.w;
      h[4]=(_Float16)c.x; h[5]=(_Float16)c.y; h[6]=(_Float16)c.z; h[7]=(_Float16)c.w;
      *(half8*)&Klds[swzi(key, d0)] = h;
    }
    // ---- stage V tile transposed: Vt[dv][k]
    #pragma unroll
    for (int it = 0; it < 2; ++it) {
      int s = t + it * 256;
      int dv = s & 63, kg = s >> 6;   // kg 0..7 across both iters
      const float* src = KVb + (size_t)(mt * 8 + kg) * 4096 + 256 + dv;
      half8 h;
      #pragma unroll
      for (int j = 0; j < 8; ++j) h[j] = (_Float16)src[j * 512];
      *(half8*)&Vt[swzi(dv, kg * 8)] = h;
    }
    __syncthreads();

    // ---- S = Q K^T  (32q x 64k per wave)
    f32x4 sc[2][4];
    #pragma unroll
    for (int kt = 0; kt < 4; ++kt) {
      half8 k0 = *(half8*)&Klds[swzi(kt * 16 + lm, lg * 8)];
      half8 k1 = *(half8*)&Klds[swzi(kt * 16 + lm, 32 + lg * 8)];
      #pragma unroll
      for (int qg = 0; qg < 2; ++qg) {
        f32x4 z = (f32x4){0.f, 0.f, 0.f, 0.f};
        z = __builtin_amdgcn_mfma_f32_16x16x32_f16(qf[qg][0], k0, z, 0, 0, 0);
        z = __builtin_amdgcn_mfma_f32_16x16x32_f16(qf[qg][1], k1, z, 0, 0, 0);
        sc[qg][kt] = z;
      }
    }

    // ---- online softmax; write P (fp16) into this wave's QP slice
    #pragma unroll
    for (int qg = 0; qg < 2; ++qg) {
      #pragma unroll
      for (int kt = 0; kt < 4; ++kt) sc[qg][kt] *= 0.125f;
      float corr[4];
      #pragma unroll
      for (int r = 0; r < 4; ++r) {
        float tm = fmaxf(fmaxf(sc[qg][0][r], sc[qg][1][r]),
                         fmaxf(sc[qg][2][r], sc[qg][3][r]));
        #pragma unroll
        for (int off = 1; off < 16; off <<= 1) tm = fmaxf(tm, __shfl_xor(tm, off, 64));
        float mnew = fmaxf(m_run[qg][r], tm);
        corr[r] = __expf(m_run[qg][r] - mnew);
        m_run[qg][r] = mnew;
        float rs = 0.f;
        #pragma unroll
        for (int kt = 0; kt < 4; ++kt) {
          float p = __expf(sc[qg][kt][r] - mnew);
          sc[qg][kt][r] = p;
          rs += p;
        }
        #pragma unroll
        for (int off = 1; off < 16; off <<= 1) rs += __shfl_xor(rs, off, 64);
        l_run[qg][r] = l_run[qg][r] * corr[r] + rs;
        #pragma unroll
        for (int kt = 0; kt < 4; ++kt)
          QP[swzi(wq + qg * 16 + lg * 4 + r, kt * 16 + lm)] = (_Float16)sc[qg][kt][r];
      }
      f32x4 cv = (f32x4){corr[0], corr[1], corr[2], corr[3]};
      #pragma unroll
      for (int dg = 0; dg < 4; ++dg) acc[qg][dg] *= cv;
    }

    // ---- O += P V   (P from own QP slice; V from Vt)
    #pragma unroll
    for (int ka = 0; ka < 2; ++ka) {
      half8 pf[2];
      #pragma unroll
      for (int qg = 0; qg < 2; ++qg)
        pf[qg] = *(half8*)&QP[swzi(wq + qg * 16 + lm, ka * 32 + lg * 8)];
      #pragma unroll
      for (int dg = 0; dg < 4; ++dg) {
        half8 vf = *(half8*)&Vt[swzi(dg * 16 + lm, ka * 32 + lg * 8)];
        #pragma unroll
        for (int qg = 0; qg < 2; ++qg)
          acc[qg][dg] = __builtin_amdgcn_mfma_f32_16x16x32_f16(pf[qg], vf, acc[qg][dg], 0, 0, 0);
      }
    }
  }

  // ---- epilogue
  float* Ob = O + ((size_t)(b * NH + hh) * NTOK + n0) * HD;
  #pragma unroll
  for (int qg = 0; qg < 2; ++qg) {
    #pragma unroll
    for (int r = 0; r < 4; ++r) {
      float inv = 1.f / l_run[qg][r];
      int q = wq + qg * 16 + lg * 4 + r;
      #pragma unroll
      for (int dg = 0; dg < 4; ++dg)
        Ob[(size_t)q * 64 + dg * 16 + lm] = acc[qg][dg][r] * inv;
    }
  }
}

// ---------------------------------------------------------------------------
// projection (fp32, unchanged from baseline)
// ---------------------------------------------------------------------------
__global__ __launch_bounds__(256) void proj_kernel(
    const float* __restrict__ A, const float* __restrict__ Wp,
    const float* __restrict__ bias, float* __restrict__ Out)
{
  const int rt = blockIdx.x;
  const int ct = blockIdx.y;
  __shared__ float As[32][68];
  __shared__ float Ws[32][68];
  const int t  = threadIdx.x;
  const int ty = t >> 4, tx = t & 15;
  float acc[4][4] = {};
  const float* Ab = A  + (size_t)rt * 64 * 256;
  const float* Wb = Wp + (size_t)ct * 64 * 256;
  for (int c0 = 0; c0 < 256; c0 += 32) {
    #pragma unroll
    for (int i = 0; i < 8; ++i) {
      int e = t + i * 256;
      int r = e >> 5, k = e & 31;
      As[k][r] = Ab[r * 256 + c0 + k];
      Ws[k][r] = Wb[r * 256 + c0 + k];
    }
    __syncthreads();
    #pragma unroll
    for (int k = 0; k < 32; ++k) {
      float4 av = *(const float4*)&As[k][ty * 4];
      float4 wv = *(const float4*)&Ws[k][tx * 4];
      float a4[4] = {av.x, av.y, av.z, av.w};
      float b4[4] = {wv.x, wv.y, wv.z, wv.w};
      #pragma unroll
      for (int i = 0; i < 4; ++i)
        #pragma unroll
        for (int j = 0; j < 4; ++j)
          acc[i][j] = fmaf(a4[i], b4[j], acc[i][j]);
    }
    __syncthreads();
  }
  #pragma unroll
  for (int i = 0; i < 4; ++i) {
    int r = rt * 64 + ty * 4 + i;
    float o[4];
    #pragma unroll
    for (int j = 0; j < 4; ++j) o[j] = acc[i][j] + bias[ct * 64 + tx * 4 + j];
    float4 o4 = make_float4(o[0], o[1], o[2], o[3]);
    *(float4*)&Out[(size_t)r * 256 + ct * 64 + tx * 4] = o4;
  }
}

// ---------------------------------------------------------------------------
extern "C" void kernel_launch(void* const* d_in, const int* in_sizes, int n_in,
                              void* d_out, int out_size, void* d_ws, size_t ws_size,
                              hipStream_t stream) {
  const float* x        = (const float*)d_in[0];
  const float* y        = (const float*)d_in[1];
  const float* q_w      = (const float*)d_in[4];
  const float* q_gamma  = (const float*)d_in[5];
  const float* q_beta   = (const float*)d_in[6];
  const float* q_mean   = (const float*)d_in[7];
  const float* q_var    = (const float*)d_in[8];
  const float* kv_w     = (const float*)d_in[9];
  const float* kv_gamma = (const float*)d_in[10];
  const float* kv_beta  = (const float*)d_in[11];
  const float* kv_mean  = (const float*)d_in[12];
  const float* kv_var   = (const float*)d_in[13];
  const float* proj_w   = (const float*)d_in[14];
  const float* proj_b   = (const float*)d_in[15];
  float* out = (float*)d_out;

  float* qbn    = (float*)d_ws;                         // B*256*4096 floats
  float* kvbn   = qbn  + (size_t)BB * CC * NTOK;        // B*128*4096 floats
  float* attout = kvbn + (size_t)BB * CKV * NTOK;       // B*4*4096*64 floats

  conv_bn_silu_kernel<256><<<dim3(64, 4, BB), 256, 0, stream>>>(
      x, q_w, q_gamma, q_beta, q_mean, q_var, qbn);
  conv_bn_silu_kernel<128><<<dim3(64, 2, BB), 256, 0, stream>>>(
      y, kv_w, kv_gamma, kv_beta, kv_mean, kv_var, kvbn);
  attn_mfma_kernel<<<dim3(32, NH, BB), 256, 0, stream>>>(qbn, kvbn, attout);
  proj_kernel<<<dim3(256, 4, 1), 256, 0, stream>>>(attout, proj_w, proj_b, out);
}

// Round 5
// 90.861 us; speedup vs baseline: 5.0497x; 1.7815x over previous
//
#include <hip/hip_runtime.h>
#include <hip/hip_bf16.h>
#include <math.h>

#define BB 4
#define NTOK 4096
#define CC 256
#define NH 4
#define HD 64
#define CKV 128

typedef _Float16 half8 __attribute__((ext_vector_type(8)));
typedef _Float16 half2v __attribute__((ext_vector_type(2)));
typedef float    f32x4 __attribute__((ext_vector_type(4)));

// cvt_pkrtz returns __fp16x2; bit_cast to our half2v
__device__ __forceinline__ half2v pkrtz(float a, float b) {
  return __builtin_bit_cast(half2v, __builtin_amdgcn_cvt_pkrtz(a, b));
}

// row-swizzled LDS index for 64-half rows: conflict-free ds_read/write_b128
__device__ __forceinline__ int swzi(int row, int d) {
  return row * 64 + (d ^ ((row & 7) << 3));
}

__device__ __forceinline__ f32x4 mfma16(half8 a, half8 b, f32x4 c) {
  return __builtin_amdgcn_mfma_f32_16x16x32_f16(a, b, c, 0, 0, 0);
}

// ---------------------------------------------------------------------------
// prep: fp16 weights with BN gamma folded; b2 = beta - mean*g; proj W fp16
// ---------------------------------------------------------------------------
__global__ __launch_bounds__(256) void prep_weights(
    const float* __restrict__ qw, const float* __restrict__ qg_, const float* __restrict__ qb,
    const float* __restrict__ qm, const float* __restrict__ qv,
    const float* __restrict__ kw, const float* __restrict__ kg_, const float* __restrict__ kb,
    const float* __restrict__ km, const float* __restrict__ kvv,
    const float* __restrict__ pw,
    _Float16* __restrict__ qWh, float* __restrict__ qB2,
    _Float16* __restrict__ kWh, float* __restrict__ kB2,
    _Float16* __restrict__ pWh)
{
  int r = blockIdx.x, c = threadIdx.x;
  if (r < 256) {
    float g = qg_[r] * rsqrtf(qv[r] + 1e-5f);
    qWh[r * 256 + c] = (_Float16)(qw[r * 256 + c] * g);
    if (c == 0) qB2[r] = qb[r] - qm[r] * g;
  } else if (r < 384) {
    int o = r - 256;
    float g = kg_[o] * rsqrtf(kvv[o] + 1e-5f);
    kWh[o * 256 + c] = (_Float16)(kw[o * 256 + c] * g);
    if (c == 0) kB2[o] = kb[o] - km[o] * g;
  } else {
    int o = r - 384;
    pWh[o * 256 + c] = (_Float16)pw[o * 256 + c];
  }
}

// ---------------------------------------------------------------------------
// transpose+cast: X f32 [b][256][4096] -> Xt fp16 [b][4096][256]
// ---------------------------------------------------------------------------
__global__ __launch_bounds__(256) void transpose_cast(
    const float* __restrict__ X, _Float16* __restrict__ Xt)
{
  const int pt = blockIdx.x, ct = blockIdx.y, b = blockIdx.z;
  __shared__ float T[64][65];
  const int t = threadIdx.x;
  const float* Xb = X + (size_t)b * CC * NTOK + (size_t)ct * 64 * NTOK + pt * 64;
  const int cr = t >> 4, pc = (t & 15) * 4;
  #pragma unroll
  for (int i = 0; i < 4; ++i) {
    float4 v = *(const float4*)&Xb[(size_t)(cr + i * 16) * NTOK + pc];
    T[cr + i * 16][pc]     = v.x;  T[cr + i * 16][pc + 1] = v.y;
    T[cr + i * 16][pc + 2] = v.z;  T[cr + i * 16][pc + 3] = v.w;
  }
  __syncthreads();
  _Float16* Ot = Xt + (size_t)b * NTOK * CC + (size_t)(pt * 64) * CC + ct * 64;
  #pragma unroll
  for (int i = 0; i < 2; ++i) {
    int u = t + i * 256;
    int p = u >> 3, ch = u & 7;
    half8 h;
    #pragma unroll
    for (int j = 0; j < 8; ++j) h[j] = (_Float16)T[ch * 8 + j][p];
    *(half8*)&Ot[(size_t)p * CC + ch * 8] = h;
  }
}

// ---------------------------------------------------------------------------
// conv1x1+BN+SiLU as fp16 MFMA GEMM. A = Xt [p][c], B = Wh [o][c] (n-major),
// D[p][o]; out fp16 [b][o][4096] at o*4096+p.
// Block: 128p x 64o, 4 waves (each 32p x 64o).
// ---------------------------------------------------------------------------
template<int COUT>
__global__ __launch_bounds__(256) void conv_mfma(
    const _Float16* __restrict__ Xt, const _Float16* __restrict__ Wh,
    const float* __restrict__ B2, _Float16* __restrict__ Y)
{
  const int ptile = blockIdx.x, otile = blockIdx.y, b = blockIdx.z;
  __shared__ _Float16 Xs[128 * 64];
  __shared__ _Float16 Ws[64 * 64];
  const int t = threadIdx.x, wave = t >> 6, lane = t & 63;
  const int lm = lane & 15, lg = lane >> 4;
  const _Float16* Xb = Xt + (size_t)b * NTOK * CC + (size_t)ptile * 128 * CC;
  const _Float16* Wb = Wh + otile * 64 * 256;
  f32x4 acc[2][4];
  #pragma unroll
  for (int m = 0; m < 2; ++m)
    #pragma unroll
    for (int n = 0; n < 4; ++n) acc[m][n] = (f32x4){0.f, 0.f, 0.f, 0.f};

  for (int c0 = 0; c0 < 256; c0 += 64) {
    __syncthreads();
    #pragma unroll
    for (int i = 0; i < 4; ++i) {
      int u = t + i * 256; int p = u >> 3, ch = u & 7;
      *(half8*)&Xs[swzi(p, ch * 8)] = *(const half8*)&Xb[(size_t)p * 256 + c0 + ch * 8];
    }
    #pragma unroll
    for (int i = 0; i < 2; ++i) {
      int u = t + i * 256; int o = u >> 3, ch = u & 7;
      *(half8*)&Ws[swzi(o, ch * 8)] = *(const half8*)&Wb[o * 256 + c0 + ch * 8];
    }
    __syncthreads();
    #pragma unroll
    for (int kh = 0; kh < 2; ++kh) {
      half8 af[2], bf[4];
      #pragma unroll
      for (int m = 0; m < 2; ++m) af[m] = *(half8*)&Xs[swzi(wave * 32 + m * 16 + lm, kh * 32 + lg * 8)];
      #pragma unroll
      for (int n = 0; n < 4; ++n) bf[n] = *(half8*)&Ws[swzi(n * 16 + lm, kh * 32 + lg * 8)];
      #pragma unroll
      for (int m = 0; m < 2; ++m)
        #pragma unroll
        for (int n = 0; n < 4; ++n)
          acc[m][n] = mfma16(af[m], bf[n], acc[m][n]);
    }
  }
  _Float16* Yb = Y + (size_t)b * COUT * NTOK;
  float b2v[4];
  #pragma unroll
  for (int n = 0; n < 4; ++n) b2v[n] = B2[otile * 64 + n * 16 + lm];
  #pragma unroll
  for (int m = 0; m < 2; ++m)
    #pragma unroll
    for (int n = 0; n < 4; ++n) {
      int o = otile * 64 + n * 16 + lm;
      float r[4];
      #pragma unroll
      for (int rr = 0; rr < 4; ++rr) {
        float v = acc[m][n][rr] + b2v[n];
        r[rr] = v / (1.f + __expf(-v));
      }
      half2v p0 = pkrtz(r[0], r[1]);
      half2v p1 = pkrtz(r[2], r[3]);
      int p = ptile * 128 + wave * 32 + m * 16 + lg * 4;
      _Float16* dst = Yb + (size_t)o * NTOK + p;
      *(half2v*)dst = p0;  *(half2v*)(dst + 2) = p1;
    }
}

// ---------------------------------------------------------------------------
// fp16 MFMA flash attention, swapped-operand layout (S^T, O^T in registers).
// Per iter: sc[qg][kt] = mfma(K_frag, Q_frag) -> S^T[k][q]; lane owns 16 k
// for its q=lane&15 -> row reduce = in-lane + 2 shfl. P packed b64 into Pl
// (per-wave rows, no barrier). PV: acc = mfma(Vt_frag, P_frag) -> O^T[d][q].
// ---------------------------------------------------------------------------
__global__ __launch_bounds__(256) void attn_mfma2(
    const _Float16* __restrict__ Q,   // [b][256*4096] fp16 scrambled conv out
    const _Float16* __restrict__ KV,  // [b][128*4096]
    _Float16* __restrict__ O)         // flat [b][h][n][d] fp16
{
  const int nt = blockIdx.x, hh = blockIdx.y, b = blockIdx.z;
  const int n0 = nt * 128;
  const int t = threadIdx.x, wave = t >> 6, lane = t & 63;
  const int lm = lane & 15, lg = lane >> 4;
  const int wq = wave * 32;
  const float SCL = 0.125f * 1.44269504f;  // scale * log2(e)

  __shared__ _Float16 Klds[64 * 64];
  __shared__ _Float16 Vt[64 * 64];
  __shared__ _Float16 Pl[128 * 64];

  const _Float16* Qb  = Q  + (size_t)b * (CC * NTOK)  + hh * 64;
  const _Float16* KVb = KV + (size_t)b * (CKV * NTOK) + hh * 64;

  // Q fragments direct from global (row n, 8 contiguous halfs per chunk)
  half8 qf[2][2];
  #pragma unroll
  for (int qg = 0; qg < 2; ++qg) {
    int n = n0 + wq + qg * 16 + lm;
    const _Float16* src = Qb + (n >> 4) * 4096 + (n & 15) * 256;
    #pragma unroll
    for (int ds = 0; ds < 2; ++ds)
      qf[qg][ds] = *(const half8*)(src + ds * 32 + lg * 8);
  }

  f32x4 acc[2][4];
  float m_run[2], l_run[2];
  #pragma unroll
  for (int qg = 0; qg < 2; ++qg) {
    m_run[qg] = -1e30f; l_run[qg] = 0.f;
    #pragma unroll
    for (int dg = 0; dg < 4; ++dg) acc[qg][dg] = (f32x4){0.f, 0.f, 0.f, 0.f};
  }

  const int dvp = (t & 31) * 2, kgv = t >> 5;  // V prefetch unit
  half8 kreg[2];
  unsigned int vreg[8];

  auto PREFETCH = [&](int mt) {
    #pragma unroll
    for (int it = 0; it < 2; ++it) {
      int s = t + it * 256; int key = s >> 3, ch = s & 7;
      kreg[it] = *(const half8*)(KVb + (size_t)(mt * 8 + (key >> 3)) * 4096 + (key & 7) * 512 + ch * 8);
    }
    const _Float16* vsrc = KVb + (size_t)(mt * 8 + kgv) * 4096 + 256 + dvp;
    #pragma unroll
    for (int j = 0; j < 8; ++j)
      vreg[j] = *(const unsigned int*)(vsrc + j * 512);
  };
  PREFETCH(0);

  for (int mt = 0; mt < 16; ++mt) {
    __syncthreads();  // previous tile's LDS consumers done
    // write staged regs -> LDS
    #pragma unroll
    for (int it = 0; it < 2; ++it) {
      int s = t + it * 256; int key = s >> 3, ch = s & 7;
      *(half8*)&Klds[swzi(key, ch * 8)] = kreg[it];
    }
    {
      half8 lo, hi;
      #pragma unroll
      for (int j = 0; j < 8; ++j) {
        half2v hv = __builtin_bit_cast(half2v, vreg[j]);
        lo[j] = hv[0]; hi[j] = hv[1];
      }
      *(half8*)&Vt[swzi(dvp,     kgv * 8)] = lo;
      *(half8*)&Vt[swzi(dvp + 1, kgv * 8)] = hi;
    }
    __syncthreads();  // LDS ready
    if (mt < 15) PREFETCH(mt + 1);  // loads hide under compute

    // S^T = mfma(K, Q): lane holds S^T[k=kt*16+lg*4+r][q=lm]
    f32x4 sc[2][4];
    #pragma unroll
    for (int kt = 0; kt < 4; ++kt) {
      half8 kf0 = *(half8*)&Klds[swzi(kt * 16 + lm, lg * 8)];
      half8 kf1 = *(half8*)&Klds[swzi(kt * 16 + lm, 32 + lg * 8)];
      #pragma unroll
      for (int qg = 0; qg < 2; ++qg) {
        f32x4 z = (f32x4){0.f, 0.f, 0.f, 0.f};
        z = mfma16(kf0, qf[qg][0], z);
        z = mfma16(kf1, qf[qg][1], z);
        sc[qg][kt] = z;
      }
    }

    // online softmax (log2 domain), defer-max THR=3
    #pragma unroll
    for (int qg = 0; qg < 2; ++qg) {
      float tm = sc[qg][0][0];
      #pragma unroll
      for (int kt = 0; kt < 4; ++kt)
        #pragma unroll
        for (int r = 0; r < 4; ++r) tm = fmaxf(tm, sc[qg][kt][r]);
      tm *= SCL;
      tm = fmaxf(tm, __shfl_xor(tm, 16, 64));
      tm = fmaxf(tm, __shfl_xor(tm, 32, 64));
      if (__any(tm > m_run[qg] + 3.0f)) {
        float mnew = fmaxf(m_run[qg], tm);
        float corr = exp2f(m_run[qg] - mnew);
        l_run[qg] *= corr;
        #pragma unroll
        for (int dg = 0; dg < 4; ++dg) acc[qg][dg] *= corr;
        m_run[qg] = mnew;
      }
      float p[4][4];
      float rs = 0.f;
      #pragma unroll
      for (int kt = 0; kt < 4; ++kt)
        #pragma unroll
        for (int r = 0; r < 4; ++r) {
          float v = exp2f(fmaf(sc[qg][kt][r], SCL, -m_run[qg]));
          p[kt][r] = v; rs += v;
        }
      rs += __shfl_xor(rs, 16, 64);
      rs += __shfl_xor(rs, 32, 64);
      l_run[qg] += rs;
      int qrow = wq + qg * 16 + lm;
      #pragma unroll
      for (int kt = 0; kt < 4; ++kt) {
        half2v a = pkrtz(p[kt][0], p[kt][1]);
        half2v c = pkrtz(p[kt][2], p[kt][3]);
        _Float16* dst = &Pl[swzi(qrow, kt * 16 + lg * 4)];
        *(half2v*)dst = a;  *(half2v*)(dst + 2) = c;
      }
    }

    // O^T += mfma(V^T, P^T): acc[qg][dg] rows d, col q=lm
    #pragma unroll
    for (int ka = 0; ka < 2; ++ka) {
      half8 pf[2];
      #pragma unroll
      for (int qg = 0; qg < 2; ++qg)
        pf[qg] = *(half8*)&Pl[swzi(wq + qg * 16 + lm, ka * 32 + lg * 8)];
      #pragma unroll
      for (int dg = 0; dg < 4; ++dg) {
        half8 vf = *(half8*)&Vt[swzi(dg * 16 + lm, ka * 32 + lg * 8)];
        #pragma unroll
        for (int qg = 0; qg < 2; ++qg)
          acc[qg][dg] = mfma16(vf, pf[qg], acc[qg][dg]);
      }
    }
  }

  // epilogue: fp16 out, 4 contiguous d per (qg,dg)
  #pragma unroll
  for (int qg = 0; qg < 2; ++qg) {
    float inv = 1.f / l_run[qg];
    int n = n0 + wq + qg * 16 + lm;
    _Float16* dst = O + ((size_t)(b * NH + hh) * NTOK + n) * 64;
    #pragma unroll
    for (int dg = 0; dg < 4; ++dg) {
      half2v p0 = pkrtz(acc[qg][dg][0] * inv, acc[qg][dg][1] * inv);
      half2v p1 = pkrtz(acc[qg][dg][2] * inv, acc[qg][dg][3] * inv);
      _Float16* d2 = dst + dg * 16 + lg * 4;
      *(half2v*)d2 = p0;  *(half2v*)(d2 + 2) = p1;
    }
  }
}

// ---------------------------------------------------------------------------
// projection: fp16 MFMA, A = attout fp16 [16384][256], B = pWh [co][ci],
// D[r][co] + bias -> f32 out.
// ---------------------------------------------------------------------------
__global__ __launch_bounds__(256) void proj_mfma(
    const _Float16* __restrict__ A, const _Float16* __restrict__ Wp,
    const float* __restrict__ bias, float* __restrict__ Out)
{
  const int rtile = blockIdx.x, ctile = blockIdx.y;
  __shared__ _Float16 As[128 * 64];
  __shared__ _Float16 Ws[64 * 64];
  const int t = threadIdx.x, wave = t >> 6, lane = t & 63;
  const int lm = lane & 15, lg = lane >> 4;
  const _Float16* Ab = A + (size_t)rtile * 128 * 256;
  const _Float16* Wb = Wp + ctile * 64 * 256;
  f32x4 acc[2][4];
  #pragma unroll
  for (int m = 0; m < 2; ++m)
    #pragma unroll
    for (int n = 0; n < 4; ++n) acc[m][n] = (f32x4){0.f, 0.f, 0.f, 0.f};

  for (int c0 = 0; c0 < 256; c0 += 64) {
    __syncthreads();
    #pragma unroll
    for (int i = 0; i < 4; ++i) {
      int u = t + i * 256; int r = u >> 3, ch = u & 7;
      *(half8*)&As[swzi(r, ch * 8)] = *(const half8*)&Ab[(size_t)r * 256 + c0 + ch * 8];
    }
    #pragma unroll
    for (int i = 0; i < 2; ++i) {
      int u = t + i * 256; int o = u >> 3, ch = u & 7;
      *(half8*)&Ws[swzi(o, ch * 8)] = *(const half8*)&Wb[o * 256 + c0 + ch * 8];
    }
    __syncthreads();
    #pragma unroll
    for (int kh = 0; kh < 2; ++kh) {
      half8 af[2], bf[4];
      #pragma unroll
      for (int m = 0; m < 2; ++m) af[m] = *(half8*)&As[swzi(wave * 32 + m * 16 + lm, kh * 32 + lg * 8)];
      #pragma unroll
      for (int n = 0; n < 4; ++n) bf[n] = *(half8*)&Ws[swzi(n * 16 + lm, kh * 32 + lg * 8)];
      #pragma unroll
      for (int m = 0; m < 2; ++m)
        #pragma unroll
        for (int n = 0; n < 4; ++n)
          acc[m][n] = mfma16(af[m], bf[n], acc[m][n]);
    }
  }
  float* Ob = Out + (size_t)rtile * 128 * 256 + ctile * 64;
  #pragma unroll
  for (int n = 0; n < 4; ++n) {
    float bia = bias[ctile * 64 + n * 16 + lm];
    #pragma unroll
    for (int m = 0; m < 2; ++m)
      #pragma unroll
      for (int rr = 0; rr < 4; ++rr)
        Ob[(size_t)(wave * 32 + m * 16 + lg * 4 + rr) * 256 + n * 16 + lm] =
            acc[m][n][rr] + bia;
  }
}

// ---------------------------------------------------------------------------
extern "C" void kernel_launch(void* const* d_in, const int* in_sizes, int n_in,
                              void* d_out, int out_size, void* d_ws, size_t ws_size,
                              hipStream_t stream) {
  const float* x        = (const float*)d_in[0];
  const float* y        = (const float*)d_in[1];
  const float* q_w      = (const float*)d_in[4];
  const float* q_gamma  = (const float*)d_in[5];
  const float* q_beta   = (const float*)d_in[6];
  const float* q_mean   = (const float*)d_in[7];
  const float* q_var    = (const float*)d_in[8];
  const float* kv_w     = (const float*)d_in[9];
  const float* kv_gamma = (const float*)d_in[10];
  const float* kv_beta  = (const float*)d_in[11];
  const float* kv_mean  = (const float*)d_in[12];
  const float* kv_var   = (const float*)d_in[13];
  const float* proj_w   = (const float*)d_in[14];
  const float* proj_b   = (const float*)d_in[15];
  float* out = (float*)d_out;

  _Float16* Xt   = (_Float16*)d_ws;                   // 4M halfs
  _Float16* Yt   = Xt   + (size_t)BB * NTOK * CC;     // 4M
  _Float16* qbn  = Yt   + (size_t)BB * NTOK * CC;     // 4M
  _Float16* kvbn = qbn  + (size_t)BB * CC * NTOK;     // 2M
  _Float16* aout = kvbn + (size_t)BB * CKV * NTOK;    // 4M
  _Float16* qWh  = aout + (size_t)BB * NH * NTOK * HD;
  _Float16* kWh  = qWh + 256 * 256;
  _Float16* pWh  = kWh + 128 * 256;
  float* qB2 = (float*)(pWh + 256 * 256);
  float* kB2 = qB2 + 256;

  prep_weights<<<640, 256, 0, stream>>>(
      q_w, q_gamma, q_beta, q_mean, q_var,
      kv_w, kv_gamma, kv_beta, kv_mean, kv_var,
      proj_w, qWh, qB2, kWh, kB2, pWh);
  transpose_cast<<<dim3(64, 4, BB), 256, 0, stream>>>(x, Xt);
  transpose_cast<<<dim3(64, 4, BB), 256, 0, stream>>>(y, Yt);
  conv_mfma<256><<<dim3(32, 4, BB), 256, 0, stream>>>(Xt, qWh, qB2, qbn);
  conv_mfma<128><<<dim3(32, 2, BB), 256, 0, stream>>>(Yt, kWh, kB2, kvbn);
  attn_mfma2<<<dim3(32, NH, BB), 256, 0, stream>>>(qbn, kvbn, aout);
  proj_mfma<<<dim3(128, 4), 256, 0, stream>>>(aout, pWh, proj_b, out);
}

// Round 6
// 75.867 us; speedup vs baseline: 6.0477x; 1.1976x over previous
//
#include <hip/hip_runtime.h>
#include <hip/hip_bf16.h>
#include <math.h>

#define BB 4
#define NTOK 4096
#define CC 256
#define NH 4
#define HD 64
#define CKV 128

typedef _Float16 half8 __attribute__((ext_vector_type(8)));
typedef _Float16 half4 __attribute__((ext_vector_type(4)));
typedef _Float16 half2v __attribute__((ext_vector_type(2)));
typedef float    f32x4 __attribute__((ext_vector_type(4)));

__device__ __forceinline__ half2v pkrtz(float a, float b) {
  return __builtin_bit_cast(half2v, __builtin_amdgcn_cvt_pkrtz(a, b));
}
// row-swizzled LDS index for 64-half rows: conflict-free ds_read/write_b128
__device__ __forceinline__ int swzi(int row, int d) {
  return row * 64 + (d ^ ((row & 7) << 3));
}
__device__ __forceinline__ f32x4 mfma16(half8 a, half8 b, f32x4 c) {
  return __builtin_amdgcn_mfma_f32_16x16x32_f16(a, b, c, 0, 0, 0);
}

// ---------------------------------------------------------------------------
// pre_all: [0,1024) transpose+cast x -> Xt fp16 [b][p][c]
//          [1024,2048) same for y -> Yt
//          [2048,2688) weight prep (BN fold, fp16 cast)
// ---------------------------------------------------------------------------
__global__ __launch_bounds__(256) void pre_all(
    const float* __restrict__ x, const float* __restrict__ y,
    const float* __restrict__ qw, const float* __restrict__ qg_, const float* __restrict__ qb,
    const float* __restrict__ qm, const float* __restrict__ qv,
    const float* __restrict__ kw, const float* __restrict__ kg_, const float* __restrict__ kb,
    const float* __restrict__ km, const float* __restrict__ kvv,
    const float* __restrict__ pw,
    _Float16* __restrict__ Xt, _Float16* __restrict__ Yt,
    _Float16* __restrict__ qWh, float* __restrict__ qB2,
    _Float16* __restrict__ kWh, float* __restrict__ kB2,
    _Float16* __restrict__ pWh)
{
  const int id = blockIdx.x;
  __shared__ float T[64][65];
  const int t = threadIdx.x;
  if (id < 2048) {
    const float* X   = (id < 1024) ? x  : y;
    _Float16*   XT   = (id < 1024) ? Xt : Yt;
    const int i = id & 1023;
    const int pt = i & 63, ct = (i >> 6) & 3, b = i >> 8;
    const float* Xb = X + (size_t)b * CC * NTOK + (size_t)ct * 64 * NTOK + pt * 64;
    const int cr = t >> 4, pc = (t & 15) * 4;
    #pragma unroll
    for (int k = 0; k < 4; ++k) {
      float4 v = *(const float4*)&Xb[(size_t)(cr + k * 16) * NTOK + pc];
      T[cr + k * 16][pc]     = v.x;  T[cr + k * 16][pc + 1] = v.y;
      T[cr + k * 16][pc + 2] = v.z;  T[cr + k * 16][pc + 3] = v.w;
    }
    __syncthreads();
    _Float16* Ot = XT + (size_t)b * NTOK * CC + (size_t)(pt * 64) * CC + ct * 64;
    #pragma unroll
    for (int k = 0; k < 2; ++k) {
      int u = t + k * 256;
      int p = u >> 3, ch = u & 7;
      half8 h;
      #pragma unroll
      for (int j = 0; j < 8; ++j) h[j] = (_Float16)T[ch * 8 + j][p];
      *(half8*)&Ot[(size_t)p * CC + ch * 8] = h;
    }
  } else {
    const int r = id - 2048;
    const int c = t;
    if (r < 256) {
      float g = qg_[r] * rsqrtf(qv[r] + 1e-5f);
      qWh[r * 256 + c] = (_Float16)(qw[r * 256 + c] * g);
      if (c == 0) qB2[r] = qb[r] - qm[r] * g;
    } else if (r < 384) {
      int o = r - 256;
      float g = kg_[o] * rsqrtf(kvv[o] + 1e-5f);
      kWh[o * 256 + c] = (_Float16)(kw[o * 256 + c] * g);
      if (c == 0) kB2[o] = kb[o] - km[o] * g;
    } else if (r < 640) {
      int o = r - 384;
      pWh[o * 256 + c] = (_Float16)pw[o * 256 + c];
    }
  }
}

// ---------------------------------------------------------------------------
// merged conv1x1+BN+SiLU fp16 MFMA GEMM (q conv: blockIdx.y<4, kv: 4..5)
// A = Xt/Yt [p][c], B = W [o][c]; out fp16 [b][o][4096] at o*4096+p.
// ---------------------------------------------------------------------------
__global__ __launch_bounds__(256) void conv_mfma_all(
    const _Float16* __restrict__ Xt, const _Float16* __restrict__ Yt,
    const _Float16* __restrict__ qWh, const float* __restrict__ qB2,
    const _Float16* __restrict__ kWh, const float* __restrict__ kB2,
    _Float16* __restrict__ qout, _Float16* __restrict__ kvout)
{
  const int ptile = blockIdx.x, oy = blockIdx.y, b = blockIdx.z;
  const bool isq = oy < 4;
  const _Float16* A  = isq ? Xt : Yt;
  const _Float16* W  = isq ? qWh : kWh;
  const float*    B2 = isq ? qB2 : kB2;
  _Float16*       Y  = isq ? qout : kvout;
  const int otile = isq ? oy : oy - 4;
  const int COUT  = isq ? 256 : 128;

  __shared__ _Float16 Xs[128 * 64];
  __shared__ _Float16 Ws[64 * 64];
  const int t = threadIdx.x, wave = t >> 6, lane = t & 63;
  const int lm = lane & 15, lg = lane >> 4;
  const _Float16* Xb = A + (size_t)b * NTOK * CC + (size_t)ptile * 128 * CC;
  const _Float16* Wb = W + otile * 64 * 256;
  f32x4 acc[2][4];
  #pragma unroll
  for (int m = 0; m < 2; ++m)
    #pragma unroll
    for (int n = 0; n < 4; ++n) acc[m][n] = (f32x4){0.f, 0.f, 0.f, 0.f};

  for (int c0 = 0; c0 < 256; c0 += 64) {
    __syncthreads();
    #pragma unroll
    for (int i = 0; i < 4; ++i) {
      int u = t + i * 256; int p = u >> 3, ch = u & 7;
      *(half8*)&Xs[swzi(p, ch * 8)] = *(const half8*)&Xb[(size_t)p * 256 + c0 + ch * 8];
    }
    #pragma unroll
    for (int i = 0; i < 2; ++i) {
      int u = t + i * 256; int o = u >> 3, ch = u & 7;
      *(half8*)&Ws[swzi(o, ch * 8)] = *(const half8*)&Wb[o * 256 + c0 + ch * 8];
    }
    __syncthreads();
    #pragma unroll
    for (int kh = 0; kh < 2; ++kh) {
      half8 af[2], bf[4];
      #pragma unroll
      for (int m = 0; m < 2; ++m) af[m] = *(half8*)&Xs[swzi(wave * 32 + m * 16 + lm, kh * 32 + lg * 8)];
      #pragma unroll
      for (int n = 0; n < 4; ++n) bf[n] = *(half8*)&Ws[swzi(n * 16 + lm, kh * 32 + lg * 8)];
      #pragma unroll
      for (int m = 0; m < 2; ++m)
        #pragma unroll
        for (int n = 0; n < 4; ++n)
          acc[m][n] = mfma16(af[m], bf[n], acc[m][n]);
    }
  }
  _Float16* Yb = Y + (size_t)b * COUT * NTOK;
  #pragma unroll
  for (int m = 0; m < 2; ++m)
    #pragma unroll
    for (int n = 0; n < 4; ++n) {
      int o = otile * 64 + n * 16 + lm;
      float b2 = B2[o];
      float r[4];
      #pragma unroll
      for (int rr = 0; rr < 4; ++rr) {
        float v = acc[m][n][rr] + b2;
        r[rr] = v / (1.f + __expf(-v));
      }
      half2v p0 = pkrtz(r[0], r[1]);
      half2v p1 = pkrtz(r[2], r[3]);
      half4 h; h[0]=p0[0]; h[1]=p0[1]; h[2]=p1[0]; h[3]=p1[1];
      int p = ptile * 128 + wave * 32 + m * 16 + lg * 4;
      *(half4*)&Yb[(size_t)o * NTOK + p] = h;
    }
}

// ---------------------------------------------------------------------------
// fp16 MFMA flash attention, swapped-operand layout (S^T, O^T in registers).
// 64 q-rows/block (16/wave), KVBLK=64. Denominator via all-ones MFMA column.
// ---------------------------------------------------------------------------
__global__ __launch_bounds__(256) void attn_mfma3(
    const _Float16* __restrict__ Q,   // [b][256*4096] fp16 scrambled conv out
    const _Float16* __restrict__ KV,  // [b][128*4096]
    _Float16* __restrict__ O)         // flat [b][h][n][d] fp16
{
  const int nt = blockIdx.x, hh = blockIdx.y, b = blockIdx.z;
  const int n0 = nt * 64;
  const int t = threadIdx.x, wave = t >> 6, lane = t & 63;
  const int lm = lane & 15, lg = lane >> 4;
  const int wq = wave * 16;
  const float SCL = 0.125f * 1.44269504f;  // scale * log2(e)

  __shared__ _Float16 Klds[64 * 64];
  __shared__ _Float16 Vt[64 * 64];
  __shared__ _Float16 Pl[64 * 64];

  const _Float16* Qb  = Q  + (size_t)b * (CC * NTOK)  + hh * 64;
  const _Float16* KVb = KV + (size_t)b * (CKV * NTOK) + hh * 64;

  // Q fragment: this wave's 16 rows (q = wq + lm)
  half8 qf[2];
  {
    int n = n0 + wq + lm;
    const _Float16* src = Qb + (n >> 4) * 4096 + (n & 15) * 256;
    qf[0] = *(const half8*)(src + lg * 8);
    qf[1] = *(const half8*)(src + 32 + lg * 8);
  }

  half8 ones;
  #pragma unroll
  for (int j = 0; j < 8; ++j) ones[j] = (_Float16)1.f;

  f32x4 acc[4], accl;
  float m_run = -1e30f;
  #pragma unroll
  for (int dg = 0; dg < 4; ++dg) acc[dg] = (f32x4){0.f, 0.f, 0.f, 0.f};
  accl = (f32x4){0.f, 0.f, 0.f, 0.f};

  const int dvp = (t & 31) * 2, kgv = t >> 5;  // V prefetch unit
  half8 kreg[2];
  unsigned int vreg[8];

  auto PREFETCH = [&](int mt) {
    #pragma unroll
    for (int it = 0; it < 2; ++it) {
      int s = t + it * 256; int key = s >> 3, ch = s & 7;
      kreg[it] = *(const half8*)(KVb + (size_t)(mt * 8 + (key >> 3)) * 4096 + (key & 7) * 512 + ch * 8);
    }
    const _Float16* vsrc = KVb + (size_t)(mt * 8 + kgv) * 4096 + 256 + dvp;
    #pragma unroll
    for (int j = 0; j < 8; ++j)
      vreg[j] = *(const unsigned int*)(vsrc + j * 512);
  };
  PREFETCH(0);

  for (int mt = 0; mt < 16; ++mt) {
    __syncthreads();  // previous tile's LDS consumers done
    #pragma unroll
    for (int it = 0; it < 2; ++it) {
      int s = t + it * 256; int key = s >> 3, ch = s & 7;
      *(half8*)&Klds[swzi(key, ch * 8)] = kreg[it];
    }
    {
      half8 lo, hi;
      #pragma unroll
      for (int j = 0; j < 8; ++j) {
        half2v hv = __builtin_bit_cast(half2v, vreg[j]);
        lo[j] = hv[0]; hi[j] = hv[1];
      }
      *(half8*)&Vt[swzi(dvp,     kgv * 8)] = lo;
      *(half8*)&Vt[swzi(dvp + 1, kgv * 8)] = hi;
    }
    __syncthreads();  // LDS ready
    if (mt < 15) PREFETCH(mt + 1);  // next-tile loads fly under compute

    // S^T = mfma(K, Q): lane holds S^T[k=kt*16+lg*4+r][q=lm]
    f32x4 sc[4];
    #pragma unroll
    for (int kt = 0; kt < 4; ++kt) {
      half8 kf0 = *(half8*)&Klds[swzi(kt * 16 + lm, lg * 8)];
      half8 kf1 = *(half8*)&Klds[swzi(kt * 16 + lm, 32 + lg * 8)];
      f32x4 z = (f32x4){0.f, 0.f, 0.f, 0.f};
      z = mfma16(kf0, qf[0], z);
      z = mfma16(kf1, qf[1], z);
      sc[kt] = z;
    }

    // row max: max3-friendly tree (8 ops) + 2 shuffles
    float t0 = fmaxf(fmaxf(sc[0][0], sc[0][1]), sc[0][2]);
    float t1 = fmaxf(fmaxf(sc[0][3], sc[1][0]), sc[1][1]);
    float t2 = fmaxf(fmaxf(sc[1][2], sc[1][3]), sc[2][0]);
    float t3 = fmaxf(fmaxf(sc[2][1], sc[2][2]), sc[2][3]);
    float t4 = fmaxf(fmaxf(sc[3][0], sc[3][1]), sc[3][2]);
    float tm = fmaxf(fmaxf(fmaxf(t0, t1), t2), fmaxf(fmaxf(t3, t4), sc[3][3]));
    tm *= SCL;
    tm = fmaxf(tm, __shfl_xor(tm, 16, 64));
    tm = fmaxf(tm, __shfl_xor(tm, 32, 64));
    if (__any(tm > m_run + 8.0f)) {   // defer-max THR=8 (log2 domain)
      float mnew = fmaxf(m_run, tm);
      float corr = exp2f(m_run - mnew);
      #pragma unroll
      for (int dg = 0; dg < 4; ++dg) acc[dg] *= corr;
      accl *= corr;
      m_run = mnew;
    }
    // P = exp2(s*SCL - m); write b64 per kt into own wave's Pl rows
    int qrow = wq + lm;
    #pragma unroll
    for (int kt = 0; kt < 4; ++kt) {
      float p0 = exp2f(fmaf(sc[kt][0], SCL, -m_run));
      float p1 = exp2f(fmaf(sc[kt][1], SCL, -m_run));
      float p2 = exp2f(fmaf(sc[kt][2], SCL, -m_run));
      float p3 = exp2f(fmaf(sc[kt][3], SCL, -m_run));
      half2v a = pkrtz(p0, p1), c = pkrtz(p2, p3);
      half4 h; h[0]=a[0]; h[1]=a[1]; h[2]=c[0]; h[3]=c[1];
      *(half4*)&Pl[swzi(qrow, kt * 16 + lg * 4)] = h;
    }

    // O^T += mfma(V^T, P^T); denominator via ones-MFMA
    #pragma unroll
    for (int ka = 0; ka < 2; ++ka) {
      half8 pf = *(half8*)&Pl[swzi(wq + lm, ka * 32 + lg * 8)];
      accl = mfma16(ones, pf, accl);
      #pragma unroll
      for (int dg = 0; dg < 4; ++dg) {
        half8 vf = *(half8*)&Vt[swzi(dg * 16 + lm, ka * 32 + lg * 8)];
        acc[dg] = mfma16(vf, pf, acc[dg]);
      }
    }
  }

  // epilogue: accl[0] = sum over all keys for q=lm
  float inv = 1.f / accl[0];
  int n = n0 + wq + lm;
  _Float16* dst = O + ((size_t)(b * NH + hh) * NTOK + n) * 64;
  #pragma unroll
  for (int dg = 0; dg < 4; ++dg) {
    half2v p0 = pkrtz(acc[dg][0] * inv, acc[dg][1] * inv);
    half2v p1 = pkrtz(acc[dg][2] * inv, acc[dg][3] * inv);
    half4 h; h[0]=p0[0]; h[1]=p0[1]; h[2]=p1[0]; h[3]=p1[1];
    *(half4*)(dst + dg * 16 + lg * 4) = h;
  }
}

// ---------------------------------------------------------------------------
// projection: fp16 MFMA, A = attout fp16 [16384][256], B = pWh [co][ci],
// D[r][co] + bias -> f32 out.
// ---------------------------------------------------------------------------
__global__ __launch_bounds__(256) void proj_mfma(
    const _Float16* __restrict__ A, const _Float16* __restrict__ Wp,
    const float* __restrict__ bias, float* __restrict__ Out)
{
  const int rtile = blockIdx.x, ctile = blockIdx.y;
  __shared__ _Float16 As[128 * 64];
  __shared__ _Float16 Ws[64 * 64];
  const int t = threadIdx.x, wave = t >> 6, lane = t & 63;
  const int lm = lane & 15, lg = lane >> 4;
  const _Float16* Ab = A + (size_t)rtile * 128 * 256;
  const _Float16* Wb = Wp + ctile * 64 * 256;
  f32x4 acc[2][4];
  #pragma unroll
  for (int m = 0; m < 2; ++m)
    #pragma unroll
    for (int n = 0; n < 4; ++n) acc[m][n] = (f32x4){0.f, 0.f, 0.f, 0.f};

  for (int c0 = 0; c0 < 256; c0 += 64) {
    __syncthreads();
    #pragma unroll
    for (int i = 0; i < 4; ++i) {
      int u = t + i * 256; int r = u >> 3, ch = u & 7;
      *(half8*)&As[swzi(r, ch * 8)] = *(const half8*)&Ab[(size_t)r * 256 + c0 + ch * 8];
    }
    #pragma unroll
    for (int i = 0; i < 2; ++i) {
      int u = t + i * 256; int o = u >> 3, ch = u & 7;
      *(half8*)&Ws[swzi(o, ch * 8)] = *(const half8*)&Wb[o * 256 + c0 + ch * 8];
    }
    __syncthreads();
    #pragma unroll
    for (int kh = 0; kh < 2; ++kh) {
      half8 af[2], bf[4];
      #pragma unroll
      for (int m = 0; m < 2; ++m) af[m] = *(half8*)&As[swzi(wave * 32 + m * 16 + lm, kh * 32 + lg * 8)];
      #pragma unroll
      for (int n = 0; n < 4; ++n) bf[n] = *(half8*)&Ws[swzi(n * 16 + lm, kh * 32 + lg * 8)];
      #pragma unroll
      for (int m = 0; m < 2; ++m)
        #pragma unroll
        for (int n = 0; n < 4; ++n)
          acc[m][n] = mfma16(af[m], bf[n], acc[m][n]);
    }
  }
  float* Ob = Out + (size_t)rtile * 128 * 256 + ctile * 64;
  #pragma unroll
  for (int n = 0; n < 4; ++n) {
    float bia = bias[ctile * 64 + n * 16 + lm];
    #pragma unroll
    for (int m = 0; m < 2; ++m)
      #pragma unroll
      for (int rr = 0; rr < 4; ++rr)
        Ob[(size_t)(wave * 32 + m * 16 + lg * 4 + rr) * 256 + n * 16 + lm] =
            acc[m][n][rr] + bia;
  }
}

// ---------------------------------------------------------------------------
extern "C" void kernel_launch(void* const* d_in, const int* in_sizes, int n_in,
                              void* d_out, int out_size, void* d_ws, size_t ws_size,
                              hipStream_t stream) {
  const float* x        = (const float*)d_in[0];
  const float* y        = (const float*)d_in[1];
  const float* q_w      = (const float*)d_in[4];
  const float* q_gamma  = (const float*)d_in[5];
  const float* q_beta   = (const float*)d_in[6];
  const float* q_mean   = (const float*)d_in[7];
  const float* q_var    = (const float*)d_in[8];
  const float* kv_w     = (const float*)d_in[9];
  const float* kv_gamma = (const float*)d_in[10];
  const float* kv_beta  = (const float*)d_in[11];
  const float* kv_mean  = (const float*)d_in[12];
  const float* kv_var   = (const float*)d_in[13];
  const float* proj_w   = (const float*)d_in[14];
  const float* proj_b   = (const float*)d_in[15];
  float* out = (float*)d_out;

  _Float16* Xt   = (_Float16*)d_ws;                   // 4M halfs
  _Float16* Yt   = Xt   + (size_t)BB * NTOK * CC;     // 4M
  _Float16* qbn  = Yt   + (size_t)BB * NTOK * CC;     // 4M
  _Float16* kvbn = qbn  + (size_t)BB * CC * NTOK;     // 2M
  _Float16* aout = kvbn + (size_t)BB * CKV * NTOK;    // 4M
  _Float16* qWh  = aout + (size_t)BB * NH * NTOK * HD;
  _Float16* kWh  = qWh + 256 * 256;
  _Float16* pWh  = kWh + 128 * 256;
  float* qB2 = (float*)(pWh + 256 * 256);
  float* kB2 = qB2 + 256;

  pre_all<<<2688, 256, 0, stream>>>(
      x, y, q_w, q_gamma, q_beta, q_mean, q_var,
      kv_w, kv_gamma, kv_beta, kv_mean, kv_var, proj_w,
      Xt, Yt, qWh, qB2, kWh, kB2, pWh);
  conv_mfma_all<<<dim3(32, 6, BB), 256, 0, stream>>>(
      Xt, Yt, qWh, qB2, kWh, kB2, qbn, kvbn);
  attn_mfma3<<<dim3(64, NH, BB), 256, 0, stream>>>(qbn, kvbn, aout);
  proj_mfma<<<dim3(128, 4), 256, 0, stream>>>(aout, pWh, proj_b, out);
}